// Round 1
// baseline (792.739 us; speedup 1.0000x reference)
//
#include <hip/hip_runtime.h>
#include <math.h>

#define S_ 256
#define B_ 16
#define D_ 512
#define V_ 32000
#define L_ 4
#define DEC_ 0.6065306597126334f   // float(exp(-1/2))

typedef short v8s __attribute__((ext_vector_type(8)));
typedef float v4f __attribute__((ext_vector_type(4)));

static __device__ __forceinline__ short f2bf(float f){
  union { float f; unsigned u; } v; v.f = f;
  unsigned r = (v.u + 0x7FFFu + ((v.u >> 16) & 1u)) >> 16;  // RNE
  return (short)(unsigned short)r;
}

// ---------------- zero scratch flags ----------------
__global__ void k_init(unsigned* counts, unsigned* bunz, float* accum){
  int g = blockIdx.x * 256 + threadIdx.x;
  if (g < S_*B_){ counts[g] = 0u; bunz[g] = 0u; }
  if (g < 2) accum[g] = 0.0f;
}

// ---------------- c_j = err_b[j] @ inf_W[j]^T + inf_b[j] (constant per launch) ----------------
__global__ void k_cj(const float* __restrict__ inf_W, const float* __restrict__ inf_b,
                     const float* __restrict__ err_b, float* __restrict__ cvec){
  int j = blockIdx.x;
  int dp = threadIdx.x; // 0..511
  const float* row = inf_W + ((size_t)j * D_ + dp) * D_;
  const float* eb = err_b + j * D_;
  float acc = inf_b[j * D_ + dp];
  for (int d = 0; d < D_; d += 4){
    float4 w = *(const float4*)(row + d);
    float4 e = *(const float4*)(eb + d);
    acc += e.x*w.x + e.y*w.y + e.z*w.z + e.w*w.w;
  }
  cvec[j * D_ + dp] = acc;
}

// ---------------- encoder GEMM: X[s*B+b][n] = emb[ids[b][s]] . enc_W[n][:] + enc_b[n] ----------------
// 64x64 tile, bf16 MFMA 16x16x32, fused embedding gather + fp32->bf16 convert.
__global__ __launch_bounds__(256) void k_gemm_enc(const int* __restrict__ ids,
                                                  const float* __restrict__ emb,
                                                  const float* __restrict__ encW,
                                                  const float* __restrict__ encb,
                                                  float* __restrict__ X){
  __shared__ __align__(16) short As[64*40];  // +8 bf16 pad -> 2-way-max bank alias
  __shared__ __align__(16) short Bs[64*40];
  __shared__ int ids_s[64];
  const int t = threadIdx.x;
  const int bm = blockIdx.x, bn = blockIdx.y;
  if (t < 64){
    int mg = bm*64 + t;
    int s = mg >> 4, b = mg & 15;       // row r = s*B + b
    ids_s[t] = ids[b * S_ + s];
  }
  __syncthreads();
  const int arow = t >> 2;
  const int kc = (t & 3) * 8;
  const int wave = t >> 6;
  const int l = t & 63;
  const int lm = l & 15;
  const int q = l >> 4;
  v4f acc[4] = {};
  for (int k0 = 0; k0 < D_; k0 += 32){
    const float* asrc = emb + (size_t)ids_s[arow] * D_ + k0 + kc;
    float4 a0 = *(const float4*)asrc;
    float4 a1 = *(const float4*)(asrc + 4);
    const float* bsrc = encW + (size_t)(bn*64 + arow) * D_ + k0 + kc;
    float4 b0 = *(const float4*)bsrc;
    float4 b1 = *(const float4*)(bsrc + 4);
    v8s av, bv;
    av[0]=f2bf(a0.x); av[1]=f2bf(a0.y); av[2]=f2bf(a0.z); av[3]=f2bf(a0.w);
    av[4]=f2bf(a1.x); av[5]=f2bf(a1.y); av[6]=f2bf(a1.z); av[7]=f2bf(a1.w);
    bv[0]=f2bf(b0.x); bv[1]=f2bf(b0.y); bv[2]=f2bf(b0.z); bv[3]=f2bf(b0.w);
    bv[4]=f2bf(b1.x); bv[5]=f2bf(b1.y); bv[6]=f2bf(b1.z); bv[7]=f2bf(b1.w);
    *(v8s*)&As[arow*40 + kc] = av;
    *(v8s*)&Bs[arow*40 + kc] = bv;
    __syncthreads();
    v8s af = *(const v8s*)&As[(wave*16 + lm)*40 + q*8];
    #pragma unroll
    for (int n = 0; n < 4; ++n){
      v8s bf = *(const v8s*)&Bs[(n*16 + lm)*40 + q*8];
      acc[n] = __builtin_amdgcn_mfma_f32_16x16x32_bf16(af, bf, acc[n], 0, 0, 0);
    }
    __syncthreads();
  }
  // C/D layout: col = lane&15, row = (lane>>4)*4 + reg  [m89/m91 verified]
  #pragma unroll
  for (int n = 0; n < 4; ++n){
    #pragma unroll
    for (int i = 0; i < 4; ++i){
      int mloc = wave*16 + q*4 + i;
      int nloc = n*16 + lm;
      int r  = bm*64 + mloc;
      int nn = bn*64 + nloc;
      X[(size_t)r * D_ + nn] = acc[n][i] + encb[nn];
    }
  }
}

// ---------------- encoder LIF scan (autonomous; parallel over b,d) ----------------
__global__ __launch_bounds__(256) void k_scan(const float* __restrict__ X,
                                              unsigned char* __restrict__ bu,
                                              unsigned* __restrict__ bunz){
  int g = blockIdx.x * 256 + threadIdx.x;  // g = b*512 + d, 0..8191
  int b = g >> 9;
  float mem = 0.0f;
  for (int s = 0; s < S_; ++s){
    float x = X[(size_t)s * (B_*D_) + g];
    mem = mem * DEC_ + x;
    float sp = (mem >= 1.0f) ? 1.0f : 0.0f;   // atan_spike(mem - 1) == (mem >= 1)
    mem *= (1.0f - sp);
    bu[(size_t)s * (B_*D_) + g] = (unsigned char)sp;
    if (sp != 0.0f) atomicOr(&bunz[s * B_ + b], 1u);
  }
}

// ---------------- main recurrent sim: one wave per batch ----------------
__device__ __forceinline__ float wave_sum(float x){
  #pragma unroll
  for (int o = 32; o > 0; o >>= 1) x += __shfl_xor(x, o);
  return x;
}

// x distributed: lane l owns d = l + 64*i. General (dense) path only.
__device__ void wave_matvec(const float* __restrict__ W, const float* __restrict__ bias,
                            const float x[8], float y[8], float* xs, int l){
  __syncthreads();
  #pragma unroll
  for (int i = 0; i < 8; ++i) xs[l + 64*i] = x[i];
  __syncthreads();
  #pragma unroll
  for (int i = 0; i < 8; ++i){
    int dp = l + 64*i;
    const float* row = W + (size_t)dp * D_;
    float acc = bias[dp];
    for (int d = 0; d < D_; d += 4){
      float4 w = *(const float4*)(row + d);
      acc += xs[d]*w.x + xs[d+1]*w.y + xs[d+2]*w.z + xs[d+3]*w.w;
    }
    y[i] = acc;
  }
}

__device__ void wave_ln(const float e[8], const float* __restrict__ g,
                        const float* __restrict__ bb, float out[8], int l){
  float s = 0.f;
  #pragma unroll
  for (int i = 0; i < 8; ++i) s += e[i];
  float m = wave_sum(s) * (1.0f/512.0f);
  float s2 = 0.f;
  #pragma unroll
  for (int i = 0; i < 8; ++i){ float d = e[i] - m; s2 += d*d; }
  float var = wave_sum(s2) * (1.0f/512.0f);
  float inv = 1.0f / sqrtf(var + 1e-5f);
  #pragma unroll
  for (int i = 0; i < 8; ++i){
    int d = l + 64*i;
    out[i] = (e[i] - m) * inv * g[d] + bb[d];
  }
}

__global__ __launch_bounds__(64) void k_sim(
    const float* __restrict__ gen_W, const float* __restrict__ gen_b,
    const float* __restrict__ inf_W, const float* __restrict__ inf_b,
    const float* __restrict__ err_g, const float* __restrict__ err_b,
    const float* __restrict__ st_g, const float* __restrict__ st_b,
    const unsigned char* __restrict__ bu8, const unsigned* __restrict__ bunz,
    const float* __restrict__ cvec,
    unsigned* __restrict__ counts, unsigned short* __restrict__ idxb,
    float* __restrict__ accum)
{
  const int b = blockIdx.x, l = threadIdx.x;
  __shared__ float xs[D_];
  __shared__ unsigned scnt;
  float st[4][8], gm[4][8], im[4][8];
  #pragma unroll
  for (int j = 0; j < 4; ++j)
    #pragma unroll
    for (int i = 0; i < 8; ++i){ st[j][i]=0.f; gm[j][i]=0.f; im[j][i]=0.f; }

  // Runtime check: are all bias vectors zero? (enables the zero-fixed-point skip)
  bool okz = true;
  #pragma unroll
  for (int j = 0; j < 4; ++j)
    #pragma unroll
    for (int i = 0; i < 8; ++i){
      int d = j*512 + l + 64*i;
      okz = okz && (gen_b[d]==0.f) && (inf_b[d]==0.f) && (err_b[d]==0.f) && (st_b[d]==0.f);
    }
  const bool bias_zero = (__all((int)okz) != 0);

  // Preload per-step "bu nonzero" flags into a 256-bit register mask.
  unsigned long long fl[4];
  #pragma unroll
  for (int w = 0; w < 4; ++w){
    unsigned v = bunz[(w*64 + l) * B_ + b];
    fl[w] = __ballot(v != 0u);
  }

  bool state_zero = true;
  float spk_acc = 0.f, memp_acc = 0.f;

  for (int t = 0; t < S_; ++t){
    bool nz = ((fl[t >> 6] >> (t & 63)) & 1ull) != 0ull;
    // zero fixed point: state==0, biases==0, bu_t==0  =>  step is identity, td_t = 0
    if (state_zero && bias_zero && !nz) continue;
    state_zero = false;

    float bu[8];
    #pragma unroll
    for (int i = 0; i < 8; ++i) bu[i] = (float)bu8[(size_t)(t*B_ + b)*D_ + l + 64*i];

    // ---- bottom-up ----
    #pragma unroll
    for (int j = 0; j < 4; ++j){
      float y[8];
      wave_matvec(gen_W + (size_t)j*D_*D_, gen_b + j*D_, st[j], y, xs, l);
      float pred[8];
      #pragma unroll
      for (int i = 0; i < 8; ++i){
        gm[j][i] = gm[j][i]*DEC_ + y[i];
        pred[i] = (gm[j][i] >= 1.0f) ? 1.0f : 0.0f;
        gm[j][i] *= (1.0f - pred[i]);
      }
      float e[8];
      #pragma unroll
      for (int i = 0; i < 8; ++i){ float v = bu[i] - pred[i]; e[i] = v > 0.f ? v : 0.f; }
      float eo[8];
      wave_ln(e, err_g + j*D_, err_b + j*D_, eo, l);
      #pragma unroll
      for (int i = 0; i < 8; ++i) spk_acc += eo[i];
      float y2[8];
      wave_matvec(inf_W + (size_t)j*D_*D_, inf_b + j*D_, eo, y2, xs, l);
      float su[8];
      #pragma unroll
      for (int i = 0; i < 8; ++i){
        im[j][i] = im[j][i]*DEC_ + y2[i];
        su[i] = (im[j][i] >= 1.0f) ? 1.0f : 0.0f;
        im[j][i] *= (1.0f - su[i]);
        memp_acc += fabsf(im[j][i]);
      }
      float tmp[8];
      #pragma unroll
      for (int i = 0; i < 8; ++i) tmp[i] = st[j][i] + su[i];
      wave_ln(tmp, st_g + j*D_, st_b + j*D_, st[j], l);
      #pragma unroll
      for (int i = 0; i < 8; ++i) bu[i] = st[j][i] > 0.f ? st[j][i] : 0.f;
    }

    // ---- top-down (err==LN(0)==err_b identically, so inf input is cvec[j]) ----
    float td[8];
    #pragma unroll
    for (int i = 0; i < 8; ++i) td[i] = st[3][i];
    #pragma unroll
    for (int j = 3; j >= 0; --j){
      float y[8];
      wave_matvec(gen_W + (size_t)j*D_*D_, gen_b + j*D_, td, y, xs, l);
      #pragma unroll
      for (int i = 0; i < 8; ++i){
        gm[j][i] = gm[j][i]*DEC_ + y[i];
        float p = (gm[j][i] >= 1.0f) ? 1.0f : 0.0f;
        gm[j][i] *= (1.0f - p);
        td[i] = p;
      }
      #pragma unroll
      for (int i = 0; i < 8; ++i){
        float c = cvec[j*D_ + l + 64*i];
        im[j][i] = im[j][i]*DEC_ + c;
        float ss = (im[j][i] >= 1.0f) ? 1.0f : 0.0f;
        im[j][i] *= (1.0f - ss);
      }
    }

    // ---- emit spike indices of final td (binary) ----
    if (l == 0) scnt = 0u;
    __syncthreads();
    unsigned base = (unsigned)(t*B_ + b) * D_;
    #pragma unroll
    for (int i = 0; i < 8; ++i){
      if (td[i] != 0.f){
        unsigned pos = atomicAdd(&scnt, 1u);
        idxb[base + pos] = (unsigned short)(l + 64*i);
      }
    }
    __syncthreads();
    if (l == 0) counts[t*B_ + b] = scnt;
  }
  spk_acc = wave_sum(spk_acc);
  memp_acc = wave_sum(memp_acc);
  if (l == 0){
    atomicAdd(&accum[0], spk_acc);
    atomicAdd(&accum[1], memp_acc);
  }
}

// ---------------- logits: out[b][s][:] = out_b + sum of out_W columns at spike indices ----------------
__global__ __launch_bounds__(256) void k_logits(const unsigned* __restrict__ counts,
                                                const unsigned short* __restrict__ idxb,
                                                const float* __restrict__ outW,
                                                const float* __restrict__ outb,
                                                float* __restrict__ out){
  __shared__ unsigned short sidx[D_];
  int bs = blockIdx.x;            // bs = b*S + s (matches output row order)
  int b = bs >> 8, s = bs & 255;
  unsigned k = counts[s * B_ + b];
  const float4* ob4 = (const float4*)outb;
  float4* o4 = (float4*)(out + (size_t)bs * V_);
  if (k == 0){
    for (int v4 = threadIdx.x; v4 < V_/4; v4 += 256) o4[v4] = ob4[v4];
  } else {
    unsigned base = (unsigned)(s * B_ + b) * D_;
    for (unsigned i = threadIdx.x; i < k; i += 256) sidx[i] = idxb[base + i];
    __syncthreads();
    for (int v4 = threadIdx.x; v4 < V_/4; v4 += 256){
      float4 a = ob4[v4];
      int v = v4 * 4;
      for (unsigned i = 0; i < k; ++i){
        int d = sidx[i];
        a.x += outW[(size_t)(v+0)*D_ + d];
        a.y += outW[(size_t)(v+1)*D_ + d];
        a.z += outW[(size_t)(v+2)*D_ + d];
        a.w += outW[(size_t)(v+3)*D_ + d];
      }
      o4[v4] = a;
    }
  }
}

__global__ void k_scalars(const float* __restrict__ accum, float* __restrict__ out){
  if (threadIdx.x == 0 && blockIdx.x == 0){
    const float inv = 1.0f / (float)(B_ * D_ * S_);   // mean over (B,D), then /S
    out[(size_t)B_ * S_ * V_ + 0] = accum[0] * inv;
    out[(size_t)B_ * S_ * V_ + 1] = accum[1] * inv;
  }
}

extern "C" void kernel_launch(void* const* d_in, const int* in_sizes, int n_in,
                              void* d_out, int out_size, void* d_ws, size_t ws_size,
                              hipStream_t stream){
  (void)in_sizes; (void)n_in; (void)out_size; (void)ws_size;
  const int*   input_ids = (const int*)d_in[0];
  const float* embedding = (const float*)d_in[1];
  const float* enc_W = (const float*)d_in[2];
  const float* enc_b = (const float*)d_in[3];
  const float* gen_W = (const float*)d_in[4];
  const float* gen_b = (const float*)d_in[5];
  const float* inf_W = (const float*)d_in[6];
  const float* inf_b = (const float*)d_in[7];
  const float* err_g = (const float*)d_in[8];
  const float* err_b = (const float*)d_in[9];
  const float* st_g  = (const float*)d_in[10];
  const float* st_b  = (const float*)d_in[11];
  const float* out_W = (const float*)d_in[12];
  const float* out_b = (const float*)d_in[13];
  float* out = (float*)d_out;
  char* ws = (char*)d_ws;

  // workspace layout (~14.05 MB total)
  float*          X      = (float*)(ws + 0);                 // 4096*512*4 = 8388608
  unsigned char*  bu     = (unsigned char*)(ws + 8388608);   // 4096*512   = 2097152
  unsigned short* idxb   = (unsigned short*)(ws + 10485760); // 4096*512*2 = 4194304
  unsigned*       counts = (unsigned*)(ws + 14680064);       // 4096*4
  unsigned*       bunz   = (unsigned*)(ws + 14696448);       // 4096*4
  float*          cvec   = (float*)(ws + 14712832);          // 4*512*4
  float*          accum  = (float*)(ws + 14721024);          // 2*4

  hipLaunchKernelGGL(k_init, dim3(16), dim3(256), 0, stream, counts, bunz, accum);
  hipLaunchKernelGGL(k_cj, dim3(4), dim3(512), 0, stream, inf_W, inf_b, err_b, cvec);
  hipLaunchKernelGGL(k_gemm_enc, dim3(64, 8), dim3(256), 0, stream,
                     input_ids, embedding, enc_W, enc_b, X);
  hipLaunchKernelGGL(k_scan, dim3(32), dim3(256), 0, stream, X, bu, bunz);
  hipLaunchKernelGGL(k_sim, dim3(16), dim3(64), 0, stream,
                     gen_W, gen_b, inf_W, inf_b, err_g, err_b, st_g, st_b,
                     bu, bunz, cvec, counts, idxb, accum);
  hipLaunchKernelGGL(k_logits, dim3(4096), dim3(256), 0, stream, counts, idxb, out_W, out_b, out);
  hipLaunchKernelGGL(k_scalars, dim3(1), dim3(64), 0, stream, accum, out);
}

// Round 2
// 710.888 us; speedup vs baseline: 1.1151x; 1.1151x over previous
//
#include <hip/hip_runtime.h>
#include <math.h>

#define S_ 256
#define B_ 16
#define D_ 512
#define V_ 32000
#define L_ 4
#define DEC_ 0.6065306597126334f   // float(exp(-1/2))

typedef short v8s __attribute__((ext_vector_type(8)));
typedef float v4f __attribute__((ext_vector_type(4)));

static __device__ __forceinline__ short f2bf(float f){
  union { float f; unsigned u; } v; v.f = f;
  unsigned r = (v.u + 0x7FFFu + ((v.u >> 16) & 1u)) >> 16;  // RNE
  return (short)(unsigned short)r;
}

// ---------------- init scratch + c_j = err_b[j] @ inf_W[j]^T + inf_b[j] ----------------
// 32 blocks x 64 threads: block = j*8 + chunk; also zeroes counts/bunz/accum.
__global__ __launch_bounds__(64) void k_cj(const float* __restrict__ inf_W,
                                           const float* __restrict__ inf_b,
                                           const float* __restrict__ err_b,
                                           float* __restrict__ cvec,
                                           unsigned* __restrict__ counts,
                                           unsigned* __restrict__ bunz,
                                           float* __restrict__ accum){
  int g = blockIdx.x * 64 + threadIdx.x;       // 0..2047
  #pragma unroll
  for (int i = 0; i < 2; ++i){
    counts[g + i*2048] = 0u;
    bunz[g + i*2048] = 0u;
  }
  if (g < 2) accum[g] = 0.0f;

  int j = blockIdx.x >> 3;                     // 0..3
  int dp = (blockIdx.x & 7) * 64 + threadIdx.x; // 0..511
  const float* row = inf_W + ((size_t)j * D_ + dp) * D_;
  const float* eb = err_b + j * D_;
  float acc = inf_b[j * D_ + dp];
  for (int d = 0; d < D_; d += 8){
    float4 w0 = *(const float4*)(row + d);
    float4 w1 = *(const float4*)(row + d + 4);
    float4 e0 = *(const float4*)(eb + d);
    float4 e1 = *(const float4*)(eb + d + 4);
    acc += e0.x*w0.x + e0.y*w0.y + e0.z*w0.z + e0.w*w0.w;
    acc += e1.x*w1.x + e1.y*w1.y + e1.z*w1.z + e1.w*w1.w;
  }
  cvec[j * D_ + dp] = acc;
}

// ---------------- encoder GEMM: X[s*B+b][n] = emb[ids[b][s]] . enc_W[n][:] + enc_b[n] ----------------
__global__ __launch_bounds__(256) void k_gemm_enc(const int* __restrict__ ids,
                                                  const float* __restrict__ emb,
                                                  const float* __restrict__ encW,
                                                  const float* __restrict__ encb,
                                                  float* __restrict__ X){
  __shared__ __align__(16) short As[64*40];
  __shared__ __align__(16) short Bs[64*40];
  __shared__ int ids_s[64];
  const int t = threadIdx.x;
  const int bm = blockIdx.x, bn = blockIdx.y;
  if (t < 64){
    int mg = bm*64 + t;
    int s = mg >> 4, b = mg & 15;       // row r = s*B + b
    ids_s[t] = ids[b * S_ + s];
  }
  __syncthreads();
  const int arow = t >> 2;
  const int kc = (t & 3) * 8;
  const int wave = t >> 6;
  const int l = t & 63;
  const int lm = l & 15;
  const int q = l >> 4;
  v4f acc[4] = {};
  for (int k0 = 0; k0 < D_; k0 += 32){
    const float* asrc = emb + (size_t)ids_s[arow] * D_ + k0 + kc;
    float4 a0 = *(const float4*)asrc;
    float4 a1 = *(const float4*)(asrc + 4);
    const float* bsrc = encW + (size_t)(bn*64 + arow) * D_ + k0 + kc;
    float4 b0 = *(const float4*)bsrc;
    float4 b1 = *(const float4*)(bsrc + 4);
    v8s av, bv;
    av[0]=f2bf(a0.x); av[1]=f2bf(a0.y); av[2]=f2bf(a0.z); av[3]=f2bf(a0.w);
    av[4]=f2bf(a1.x); av[5]=f2bf(a1.y); av[6]=f2bf(a1.z); av[7]=f2bf(a1.w);
    bv[0]=f2bf(b0.x); bv[1]=f2bf(b0.y); bv[2]=f2bf(b0.z); bv[3]=f2bf(b0.w);
    bv[4]=f2bf(b1.x); bv[5]=f2bf(b1.y); bv[6]=f2bf(b1.z); bv[7]=f2bf(b1.w);
    *(v8s*)&As[arow*40 + kc] = av;
    *(v8s*)&Bs[arow*40 + kc] = bv;
    __syncthreads();
    v8s af = *(const v8s*)&As[(wave*16 + lm)*40 + q*8];
    #pragma unroll
    for (int n = 0; n < 4; ++n){
      v8s bf = *(const v8s*)&Bs[(n*16 + lm)*40 + q*8];
      acc[n] = __builtin_amdgcn_mfma_f32_16x16x32_bf16(af, bf, acc[n], 0, 0, 0);
    }
    __syncthreads();
  }
  #pragma unroll
  for (int n = 0; n < 4; ++n){
    #pragma unroll
    for (int i = 0; i < 4; ++i){
      int mloc = wave*16 + q*4 + i;
      int nloc = n*16 + lm;
      int r  = bm*64 + mloc;
      int nn = bn*64 + nloc;
      X[(size_t)r * D_ + nn] = acc[n][i] + encb[nn];
    }
  }
}

// ---------------- encoder LIF scan: 128 blocks x 64, 8-deep load pipeline ----------------
__global__ __launch_bounds__(64) void k_scan(const float* __restrict__ X,
                                             unsigned char* __restrict__ bu,
                                             unsigned* __restrict__ bunz){
  int g = blockIdx.x * 64 + threadIdx.x;   // g = b*512 + d, 0..8191
  int b = g >> 9;
  float mem = 0.0f;
  for (int s0 = 0; s0 < S_; s0 += 8){
    float x[8];
    #pragma unroll
    for (int i = 0; i < 8; ++i) x[i] = X[(size_t)(s0 + i) * (B_*D_) + g];
    #pragma unroll
    for (int i = 0; i < 8; ++i){
      mem = mem * DEC_ + x[i];
      float sp = (mem >= 1.0f) ? 1.0f : 0.0f;   // atan_spike(mem - 1) == (mem >= 1)
      mem *= (1.0f - sp);
      bu[(size_t)(s0 + i) * (B_*D_) + g] = (unsigned char)sp;
      if (sp != 0.0f) atomicOr(&bunz[(s0 + i) * B_ + b], 1u);
    }
  }
}

// ---------------- main recurrent sim: one wave per batch ----------------
__device__ __forceinline__ float wave_sum(float x){
  #pragma unroll
  for (int o = 32; o > 0; o >>= 1) x += __shfl_xor(x, o);
  return x;
}

__device__ void wave_matvec(const float* __restrict__ W, const float* __restrict__ bias,
                            const float x[8], float y[8], float* xs, int l){
  __syncthreads();
  #pragma unroll
  for (int i = 0; i < 8; ++i) xs[l + 64*i] = x[i];
  __syncthreads();
  #pragma unroll
  for (int i = 0; i < 8; ++i){
    int dp = l + 64*i;
    const float* row = W + (size_t)dp * D_;
    float acc = bias[dp];
    for (int d = 0; d < D_; d += 4){
      float4 w = *(const float4*)(row + d);
      acc += xs[d]*w.x + xs[d+1]*w.y + xs[d+2]*w.z + xs[d+3]*w.w;
    }
    y[i] = acc;
  }
}

__device__ void wave_ln(const float e[8], const float* __restrict__ g,
                        const float* __restrict__ bb, float out[8], int l){
  float s = 0.f;
  #pragma unroll
  for (int i = 0; i < 8; ++i) s += e[i];
  float m = wave_sum(s) * (1.0f/512.0f);
  float s2 = 0.f;
  #pragma unroll
  for (int i = 0; i < 8; ++i){ float d = e[i] - m; s2 += d*d; }
  float var = wave_sum(s2) * (1.0f/512.0f);
  float inv = 1.0f / sqrtf(var + 1e-5f);
  #pragma unroll
  for (int i = 0; i < 8; ++i){
    int d = l + 64*i;
    out[i] = (e[i] - m) * inv * g[d] + bb[d];
  }
}

__global__ __launch_bounds__(64) void k_sim(
    const float* __restrict__ gen_W, const float* __restrict__ gen_b,
    const float* __restrict__ inf_W, const float* __restrict__ inf_b,
    const float* __restrict__ err_g, const float* __restrict__ err_b,
    const float* __restrict__ st_g, const float* __restrict__ st_b,
    const unsigned char* __restrict__ bu8, const unsigned* __restrict__ bunz,
    const float* __restrict__ cvec,
    unsigned* __restrict__ counts, unsigned short* __restrict__ idxb,
    float* __restrict__ accum)
{
  const int b = blockIdx.x, l = threadIdx.x;
  __shared__ float xs[D_];
  __shared__ unsigned scnt;
  float st[4][8], gm[4][8], im[4][8];
  #pragma unroll
  for (int j = 0; j < 4; ++j)
    #pragma unroll
    for (int i = 0; i < 8; ++i){ st[j][i]=0.f; gm[j][i]=0.f; im[j][i]=0.f; }

  bool okz = true;
  #pragma unroll
  for (int j = 0; j < 4; ++j)
    #pragma unroll
    for (int i = 0; i < 8; ++i){
      int d = j*512 + l + 64*i;
      okz = okz && (gen_b[d]==0.f) && (inf_b[d]==0.f) && (err_b[d]==0.f) && (st_b[d]==0.f);
    }
  const bool bias_zero = (__all((int)okz) != 0);

  unsigned long long fl[4];
  #pragma unroll
  for (int w = 0; w < 4; ++w){
    unsigned v = bunz[(w*64 + l) * B_ + b];
    fl[w] = __ballot(v != 0u);
  }

  bool state_zero = true;
  float spk_acc = 0.f, memp_acc = 0.f;

  for (int t = 0; t < S_; ++t){
    bool nz = ((fl[t >> 6] >> (t & 63)) & 1ull) != 0ull;
    if (state_zero && bias_zero && !nz) continue;   // zero fixed point: step is identity, td_t = 0
    state_zero = false;

    float bu[8];
    #pragma unroll
    for (int i = 0; i < 8; ++i) bu[i] = (float)bu8[(size_t)(t*B_ + b)*D_ + l + 64*i];

    // ---- bottom-up ----
    #pragma unroll
    for (int j = 0; j < 4; ++j){
      float y[8];
      wave_matvec(gen_W + (size_t)j*D_*D_, gen_b + j*D_, st[j], y, xs, l);
      float pred[8];
      #pragma unroll
      for (int i = 0; i < 8; ++i){
        gm[j][i] = gm[j][i]*DEC_ + y[i];
        pred[i] = (gm[j][i] >= 1.0f) ? 1.0f : 0.0f;
        gm[j][i] *= (1.0f - pred[i]);
      }
      float e[8];
      #pragma unroll
      for (int i = 0; i < 8; ++i){ float v = bu[i] - pred[i]; e[i] = v > 0.f ? v : 0.f; }
      float eo[8];
      wave_ln(e, err_g + j*D_, err_b + j*D_, eo, l);
      #pragma unroll
      for (int i = 0; i < 8; ++i) spk_acc += eo[i];
      float y2[8];
      wave_matvec(inf_W + (size_t)j*D_*D_, inf_b + j*D_, eo, y2, xs, l);
      float su[8];
      #pragma unroll
      for (int i = 0; i < 8; ++i){
        im[j][i] = im[j][i]*DEC_ + y2[i];
        su[i] = (im[j][i] >= 1.0f) ? 1.0f : 0.0f;
        im[j][i] *= (1.0f - su[i]);
        memp_acc += fabsf(im[j][i]);
      }
      float tmp[8];
      #pragma unroll
      for (int i = 0; i < 8; ++i) tmp[i] = st[j][i] + su[i];
      wave_ln(tmp, st_g + j*D_, st_b + j*D_, st[j], l);
      #pragma unroll
      for (int i = 0; i < 8; ++i) bu[i] = st[j][i] > 0.f ? st[j][i] : 0.f;
    }

    // ---- top-down (err == LN(0) == err_b identically, so inf input is cvec[j]) ----
    float td[8];
    #pragma unroll
    for (int i = 0; i < 8; ++i) td[i] = st[3][i];
    #pragma unroll
    for (int j = 3; j >= 0; --j){
      float y[8];
      wave_matvec(gen_W + (size_t)j*D_*D_, gen_b + j*D_, td, y, xs, l);
      #pragma unroll
      for (int i = 0; i < 8; ++i){
        gm[j][i] = gm[j][i]*DEC_ + y[i];
        float p = (gm[j][i] >= 1.0f) ? 1.0f : 0.0f;
        gm[j][i] *= (1.0f - p);
        td[i] = p;
      }
      #pragma unroll
      for (int i = 0; i < 8; ++i){
        float c = cvec[j*D_ + l + 64*i];
        im[j][i] = im[j][i]*DEC_ + c;
        float ss = (im[j][i] >= 1.0f) ? 1.0f : 0.0f;
        im[j][i] *= (1.0f - ss);
      }
    }

    if (l == 0) scnt = 0u;
    __syncthreads();
    unsigned base = (unsigned)(t*B_ + b) * D_;
    #pragma unroll
    for (int i = 0; i < 8; ++i){
      if (td[i] != 0.f){
        unsigned pos = atomicAdd(&scnt, 1u);
        idxb[base + pos] = (unsigned short)(l + 64*i);
      }
    }
    __syncthreads();
    if (l == 0) counts[t*B_ + b] = scnt;
  }
  spk_acc = wave_sum(spk_acc);
  memp_acc = wave_sum(memp_acc);
  if (l == 0){
    atomicAdd(&accum[0], spk_acc);
    atomicAdd(&accum[1], memp_acc);
  }
}

// ---------------- logits (+ scalar epilogue in block 0) ----------------
__global__ __launch_bounds__(256) void k_logits(const unsigned* __restrict__ counts,
                                                const unsigned short* __restrict__ idxb,
                                                const float* __restrict__ outW,
                                                const float* __restrict__ outb,
                                                const float* __restrict__ accum,
                                                float* __restrict__ out){
  __shared__ unsigned short sidx[D_];
  int bs = blockIdx.x;            // bs = b*S + s (output row order)
  int b = bs >> 8, s = bs & 255;
  if (bs == 0 && threadIdx.x == 0){
    const float inv = 1.0f / (float)(B_ * D_ * S_);   // mean over (B,D), then /S
    out[(size_t)B_ * S_ * V_ + 0] = accum[0] * inv;
    out[(size_t)B_ * S_ * V_ + 1] = accum[1] * inv;
  }
  unsigned k = counts[s * B_ + b];
  const float4* ob4 = (const float4*)outb;
  float4* o4 = (float4*)(out + (size_t)bs * V_);
  if (k == 0){
    #pragma unroll 4
    for (int v4 = threadIdx.x; v4 < V_/4; v4 += 256) o4[v4] = ob4[v4];
  } else {
    unsigned base = (unsigned)(s * B_ + b) * D_;
    for (unsigned i = threadIdx.x; i < k; i += 256) sidx[i] = idxb[base + i];
    __syncthreads();
    for (int v4 = threadIdx.x; v4 < V_/4; v4 += 256){
      float4 a = ob4[v4];
      int v = v4 * 4;
      for (unsigned i = 0; i < k; ++i){
        int d = sidx[i];
        a.x += outW[(size_t)(v+0)*D_ + d];
        a.y += outW[(size_t)(v+1)*D_ + d];
        a.z += outW[(size_t)(v+2)*D_ + d];
        a.w += outW[(size_t)(v+3)*D_ + d];
      }
      o4[v4] = a;
    }
  }
}

extern "C" void kernel_launch(void* const* d_in, const int* in_sizes, int n_in,
                              void* d_out, int out_size, void* d_ws, size_t ws_size,
                              hipStream_t stream){
  (void)in_sizes; (void)n_in; (void)out_size; (void)ws_size;
  const int*   input_ids = (const int*)d_in[0];
  const float* embedding = (const float*)d_in[1];
  const float* enc_W = (const float*)d_in[2];
  const float* enc_b = (const float*)d_in[3];
  const float* gen_W = (const float*)d_in[4];
  const float* gen_b = (const float*)d_in[5];
  const float* inf_W = (const float*)d_in[6];
  const float* inf_b = (const float*)d_in[7];
  const float* err_g = (const float*)d_in[8];
  const float* err_b = (const float*)d_in[9];
  const float* st_g  = (const float*)d_in[10];
  const float* st_b  = (const float*)d_in[11];
  const float* out_W = (const float*)d_in[12];
  const float* out_b = (const float*)d_in[13];
  float* out = (float*)d_out;
  char* ws = (char*)d_ws;

  float*          X      = (float*)(ws + 0);                 // 4096*512*4 = 8388608
  unsigned char*  bu     = (unsigned char*)(ws + 8388608);   // 4096*512   = 2097152
  unsigned short* idxb   = (unsigned short*)(ws + 10485760); // 4096*512*2 = 4194304
  unsigned*       counts = (unsigned*)(ws + 14680064);       // 4096*4
  unsigned*       bunz   = (unsigned*)(ws + 14696448);       // 4096*4
  float*          cvec   = (float*)(ws + 14712832);          // 4*512*4
  float*          accum  = (float*)(ws + 14721024);          // 2*4

  hipLaunchKernelGGL(k_cj, dim3(32), dim3(64), 0, stream,
                     inf_W, inf_b, err_b, cvec, counts, bunz, accum);
  hipLaunchKernelGGL(k_gemm_enc, dim3(64, 8), dim3(256), 0, stream,
                     input_ids, embedding, enc_W, enc_b, X);
  hipLaunchKernelGGL(k_scan, dim3(128), dim3(64), 0, stream, X, bu, bunz);
  hipLaunchKernelGGL(k_sim, dim3(16), dim3(64), 0, stream,
                     gen_W, gen_b, inf_W, inf_b, err_g, err_b, st_g, st_b,
                     bu, bunz, cvec, counts, idxb, accum);
  hipLaunchKernelGGL(k_logits, dim3(4096), dim3(256), 0, stream,
                     counts, idxb, out_W, out_b, accum, out);
}

// Round 4
// 704.393 us; speedup vs baseline: 1.1254x; 1.0092x over previous
//
#include <hip/hip_runtime.h>
#include <math.h>

#define S_ 256
#define B_ 16
#define D_ 512
#define V_ 32000
#define L_ 4
#define DEC_ 0.6065306597126334f   // float(exp(-1/2))

typedef short v8s __attribute__((ext_vector_type(8)));
typedef float v4f __attribute__((ext_vector_type(4)));

static __device__ __forceinline__ short f2bf(float f){
  union { float f; unsigned u; } v; v.f = f;
  unsigned r = (v.u + 0x7FFFu + ((v.u >> 16) & 1u)) >> 16;  // RNE
  return (short)(unsigned short)r;
}

// ---------------- encoder GEMM + scratch zero-init ----------------
// X[s*B+b][n] = emb[ids[b][s]] . enc_W[n][:] + enc_b[n]
__global__ __launch_bounds__(256) void k_gemm_enc(const int* __restrict__ ids,
                                                  const float* __restrict__ emb,
                                                  const float* __restrict__ encW,
                                                  const float* __restrict__ encb,
                                                  float* __restrict__ X,
                                                  unsigned* __restrict__ counts,
                                                  unsigned* __restrict__ bunz,
                                                  float* __restrict__ accum){
  __shared__ __align__(16) short As[64*40];
  __shared__ __align__(16) short Bs[64*40];
  __shared__ int ids_s[64];
  const int t = threadIdx.x;
  const int bm = blockIdx.x, bn = blockIdx.y;
  // zero-init scratch (k_scan/k_sim run after this kernel completes)
  if (bn == 0 && bm < 16){
    int g = bm*256 + t;
    counts[g] = 0u;
    bunz[g] = 0u;
    if (g < 2) accum[g] = 0.0f;
  }
  if (t < 64){
    int mg = bm*64 + t;
    int s = mg >> 4, b = mg & 15;       // row r = s*B + b
    ids_s[t] = ids[b * S_ + s];
  }
  __syncthreads();
  const int arow = t >> 2;
  const int kc = (t & 3) * 8;
  const int wave = t >> 6;
  const int l = t & 63;
  const int lm = l & 15;
  const int q = l >> 4;
  v4f acc[4] = {};
  for (int k0 = 0; k0 < D_; k0 += 32){
    const float* asrc = emb + (size_t)ids_s[arow] * D_ + k0 + kc;
    float4 a0 = *(const float4*)asrc;
    float4 a1 = *(const float4*)(asrc + 4);
    const float* bsrc = encW + (size_t)(bn*64 + arow) * D_ + k0 + kc;
    float4 b0 = *(const float4*)bsrc;
    float4 b1 = *(const float4*)(bsrc + 4);
    v8s av, bv;
    av[0]=f2bf(a0.x); av[1]=f2bf(a0.y); av[2]=f2bf(a0.z); av[3]=f2bf(a0.w);
    av[4]=f2bf(a1.x); av[5]=f2bf(a1.y); av[6]=f2bf(a1.z); av[7]=f2bf(a1.w);
    bv[0]=f2bf(b0.x); bv[1]=f2bf(b0.y); bv[2]=f2bf(b0.z); bv[3]=f2bf(b0.w);
    bv[4]=f2bf(b1.x); bv[5]=f2bf(b1.y); bv[6]=f2bf(b1.z); bv[7]=f2bf(b1.w);
    *(v8s*)&As[arow*40 + kc] = av;
    *(v8s*)&Bs[arow*40 + kc] = bv;
    __syncthreads();
    v8s af = *(const v8s*)&As[(wave*16 + lm)*40 + q*8];
    #pragma unroll
    for (int n = 0; n < 4; ++n){
      v8s bf = *(const v8s*)&Bs[(n*16 + lm)*40 + q*8];
      acc[n] = __builtin_amdgcn_mfma_f32_16x16x32_bf16(af, bf, acc[n], 0, 0, 0);
    }
    __syncthreads();
  }
  // C/D layout: col = lane&15, row = (lane>>4)*4 + reg  [m89/m91 verified]
  #pragma unroll
  for (int n = 0; n < 4; ++n){
    #pragma unroll
    for (int i = 0; i < 4; ++i){
      int mloc = wave*16 + q*4 + i;
      int nloc = n*16 + lm;
      int r  = bm*64 + mloc;
      int nn = bn*64 + nloc;
      X[(size_t)r * D_ + nn] = acc[n][i] + encb[nn];
    }
  }
}

// ---------------- encoder LIF scan (blocks 0..127) + cvec compute (blocks 128..159) ----------------
// cvec: c_j = err_b[j] @ inf_W[j]^T + inf_b[j]  (constant per launch; used by k_sim top-down)
__global__ __launch_bounds__(64) void k_scan(const float* __restrict__ X,
                                             unsigned char* __restrict__ bu,
                                             unsigned* __restrict__ bunz,
                                             const float* __restrict__ inf_W,
                                             const float* __restrict__ inf_b,
                                             const float* __restrict__ err_b,
                                             float* __restrict__ cvec){
  int bx = blockIdx.x;
  if (bx >= 128){
    int r = bx - 128;                       // 0..31
    int j = r >> 3;
    int dp = (r & 7) * 64 + threadIdx.x;    // 0..511
    const float* row = inf_W + ((size_t)j * D_ + dp) * D_;
    const float* eb = err_b + j * D_;
    float acc = inf_b[j * D_ + dp];
    for (int d = 0; d < D_; d += 8){
      float4 w0 = *(const float4*)(row + d);
      float4 w1 = *(const float4*)(row + d + 4);
      float4 e0 = *(const float4*)(eb + d);
      float4 e1 = *(const float4*)(eb + d + 4);
      acc += e0.x*w0.x + e0.y*w0.y + e0.z*w0.z + e0.w*w0.w;
      acc += e1.x*w1.x + e1.y*w1.y + e1.z*w1.z + e1.w*w1.w;
    }
    cvec[j * D_ + dp] = acc;
    return;
  }
  int g = bx * 64 + threadIdx.x;   // g = b*512 + d, 0..8191
  int b = g >> 9;
  float mem = 0.0f;
  for (int s0 = 0; s0 < S_; s0 += 8){
    float x[8];
    #pragma unroll
    for (int i = 0; i < 8; ++i) x[i] = X[(size_t)(s0 + i) * (B_*D_) + g];
    #pragma unroll
    for (int i = 0; i < 8; ++i){
      mem = mem * DEC_ + x[i];
      float sp = (mem >= 1.0f) ? 1.0f : 0.0f;   // atan_spike(mem - 1) == (mem >= 1)
      mem *= (1.0f - sp);
      bu[(size_t)(s0 + i) * (B_*D_) + g] = (unsigned char)sp;
      if (sp != 0.0f) atomicOr(&bunz[(s0 + i) * B_ + b], 1u);
    }
  }
}

// ---------------- main recurrent sim: one wave per batch ----------------
__device__ __forceinline__ float wave_sum(float x){
  #pragma unroll
  for (int o = 32; o > 0; o >>= 1) x += __shfl_xor(x, o);
  return x;
}

__device__ void wave_matvec(const float* __restrict__ W, const float* __restrict__ bias,
                            const float x[8], float y[8], float* xs, int l){
  __syncthreads();
  #pragma unroll
  for (int i = 0; i < 8; ++i) xs[l + 64*i] = x[i];
  __syncthreads();
  #pragma unroll
  for (int i = 0; i < 8; ++i){
    int dp = l + 64*i;
    const float* row = W + (size_t)dp * D_;
    float acc = bias[dp];
    for (int d = 0; d < D_; d += 4){
      float4 w = *(const float4*)(row + d);
      acc += xs[d]*w.x + xs[d+1]*w.y + xs[d+2]*w.z + xs[d+3]*w.w;
    }
    y[i] = acc;
  }
}

__device__ void wave_ln(const float e[8], const float* __restrict__ g,
                        const float* __restrict__ bb, float out[8], int l){
  float s = 0.f;
  #pragma unroll
  for (int i = 0; i < 8; ++i) s += e[i];
  float m = wave_sum(s) * (1.0f/512.0f);
  float s2 = 0.f;
  #pragma unroll
  for (int i = 0; i < 8; ++i){ float d = e[i] - m; s2 += d*d; }
  float var = wave_sum(s2) * (1.0f/512.0f);
  float inv = 1.0f / sqrtf(var + 1e-5f);
  #pragma unroll
  for (int i = 0; i < 8; ++i){
    int d = l + 64*i;
    out[i] = (e[i] - m) * inv * g[d] + bb[d];
  }
}

__global__ __launch_bounds__(64) void k_sim(
    const float* __restrict__ gen_W, const float* __restrict__ gen_b,
    const float* __restrict__ inf_W, const float* __restrict__ inf_b,
    const float* __restrict__ err_g, const float* __restrict__ err_b,
    const float* __restrict__ st_g, const float* __restrict__ st_b,
    const unsigned char* __restrict__ bu8, const unsigned* __restrict__ bunz,
    const float* __restrict__ cvec,
    unsigned* __restrict__ counts, unsigned short* __restrict__ idxb,
    float* __restrict__ accum)
{
  const int b = blockIdx.x, l = threadIdx.x;
  __shared__ float xs[D_];
  __shared__ unsigned scnt;
  float st[4][8], gm[4][8], im[4][8];
  #pragma unroll
  for (int j = 0; j < 4; ++j)
    #pragma unroll
    for (int i = 0; i < 8; ++i){ st[j][i]=0.f; gm[j][i]=0.f; im[j][i]=0.f; }

  bool okz = true;
  #pragma unroll
  for (int j = 0; j < 4; ++j)
    #pragma unroll
    for (int i = 0; i < 8; ++i){
      int d = j*512 + l + 64*i;
      okz = okz && (gen_b[d]==0.f) && (inf_b[d]==0.f) && (err_b[d]==0.f) && (st_b[d]==0.f);
    }
  const bool bias_zero = (__all((int)okz) != 0);

  unsigned long long fl[4];
  #pragma unroll
  for (int w = 0; w < 4; ++w){
    unsigned v = bunz[(w*64 + l) * B_ + b];
    fl[w] = __ballot(v != 0u);
  }

  bool state_zero = true;
  float spk_acc = 0.f, memp_acc = 0.f;

  for (int t = 0; t < S_; ++t){
    bool nz = ((fl[t >> 6] >> (t & 63)) & 1ull) != 0ull;
    if (state_zero && bias_zero && !nz) continue;   // zero fixed point: step is identity, td_t = 0
    state_zero = false;

    float bu[8];
    #pragma unroll
    for (int i = 0; i < 8; ++i) bu[i] = (float)bu8[(size_t)(t*B_ + b)*D_ + l + 64*i];

    // ---- bottom-up ----
    #pragma unroll
    for (int j = 0; j < 4; ++j){
      float y[8];
      wave_matvec(gen_W + (size_t)j*D_*D_, gen_b + j*D_, st[j], y, xs, l);
      float pred[8];
      #pragma unroll
      for (int i = 0; i < 8; ++i){
        gm[j][i] = gm[j][i]*DEC_ + y[i];
        pred[i] = (gm[j][i] >= 1.0f) ? 1.0f : 0.0f;
        gm[j][i] *= (1.0f - pred[i]);
      }
      float e[8];
      #pragma unroll
      for (int i = 0; i < 8; ++i){ float v = bu[i] - pred[i]; e[i] = v > 0.f ? v : 0.f; }
      float eo[8];
      wave_ln(e, err_g + j*D_, err_b + j*D_, eo, l);
      #pragma unroll
      for (int i = 0; i < 8; ++i) spk_acc += eo[i];
      float y2[8];
      wave_matvec(inf_W + (size_t)j*D_*D_, inf_b + j*D_, eo, y2, xs, l);
      float su[8];
      #pragma unroll
      for (int i = 0; i < 8; ++i){
        im[j][i] = im[j][i]*DEC_ + y2[i];
        su[i] = (im[j][i] >= 1.0f) ? 1.0f : 0.0f;
        im[j][i] *= (1.0f - su[i]);
        memp_acc += fabsf(im[j][i]);
      }
      float tmp[8];
      #pragma unroll
      for (int i = 0; i < 8; ++i) tmp[i] = st[j][i] + su[i];
      wave_ln(tmp, st_g + j*D_, st_b + j*D_, st[j], l);
      #pragma unroll
      for (int i = 0; i < 8; ++i) bu[i] = st[j][i] > 0.f ? st[j][i] : 0.f;
    }

    // ---- top-down (err == LN(0) == err_b identically, so inf input is cvec[j]) ----
    float td[8];
    #pragma unroll
    for (int i = 0; i < 8; ++i) td[i] = st[3][i];
    #pragma unroll
    for (int j = 3; j >= 0; --j){
      float y[8];
      wave_matvec(gen_W + (size_t)j*D_*D_, gen_b + j*D_, td, y, xs, l);
      #pragma unroll
      for (int i = 0; i < 8; ++i){
        gm[j][i] = gm[j][i]*DEC_ + y[i];
        float p = (gm[j][i] >= 1.0f) ? 1.0f : 0.0f;
        gm[j][i] *= (1.0f - p);
        td[i] = p;
      }
      #pragma unroll
      for (int i = 0; i < 8; ++i){
        float c = cvec[j*D_ + l + 64*i];
        im[j][i] = im[j][i]*DEC_ + c;
        float ss = (im[j][i] >= 1.0f) ? 1.0f : 0.0f;
        im[j][i] *= (1.0f - ss);
      }
    }

    if (l == 0) scnt = 0u;
    __syncthreads();
    unsigned base = (unsigned)(t*B_ + b) * D_;
    #pragma unroll
    for (int i = 0; i < 8; ++i){
      if (td[i] != 0.f){
        unsigned pos = atomicAdd(&scnt, 1u);
        idxb[base + pos] = (unsigned short)(l + 64*i);
      }
    }
    __syncthreads();
    if (l == 0) counts[t*B_ + b] = scnt;
  }
  spk_acc = wave_sum(spk_acc);
  memp_acc = wave_sum(memp_acc);
  if (l == 0){
    atomicAdd(&accum[0], spk_acc);
    atomicAdd(&accum[1], memp_acc);
  }
}

// ---------------- logits: column-chunk-resident out_b, nontemporal row stream ----------------
// grid = 25 col-chunks x 128 row-groups; block = 1 wave (64 threads).
// Each block holds its 1280-col slice of out_b in registers (5 x v4f/lane),
// then streams it to 32 rows; k>0 rows add out_W column-gather corrections.
__global__ __launch_bounds__(64) void k_logits(const unsigned* __restrict__ counts,
                                               const unsigned short* __restrict__ idxb,
                                               const float* __restrict__ outW,
                                               const float* __restrict__ outb,
                                               const float* __restrict__ accum,
                                               float* __restrict__ out){
  const int chunk = blockIdx.x % 25;
  const int rg = blockIdx.x / 25;
  const int lane = threadIdx.x;
  if (blockIdx.x == 0 && lane == 0){
    const float inv = 1.0f / (float)(B_ * D_ * S_);   // mean over (B,D), then /S
    out[(size_t)B_ * S_ * V_ + 0] = accum[0] * inv;
    out[(size_t)B_ * S_ * V_ + 1] = accum[1] * inv;
  }
  const int colbase = chunk * 1280;
  v4f pay[5];
  #pragma unroll
  for (int k = 0; k < 5; ++k)
    pay[k] = *(const v4f*)(outb + colbase + k*256 + lane*4);

  // prefetch this block's 32 row-counts (lane r holds count for row rg*32+r)
  int prow = rg*32 + (lane & 31);
  unsigned myc = counts[(prow & 255) * B_ + (prow >> 8)];

  for (int r = 0; r < 32; ++r){
    int row = rg*32 + r;                      // row = b*S + s (output order)
    unsigned cnt = (unsigned)__shfl((int)myc, r);
    float* dst = out + (size_t)row * V_ + colbase;
    if (cnt == 0){
      #pragma unroll
      for (int k = 0; k < 5; ++k)
        __builtin_nontemporal_store(pay[k], (v4f*)(dst + k*256 + lane*4));
    } else {
      int s = row & 255, b = row >> 8;
      unsigned base = (unsigned)(s * B_ + b) * D_;
      v4f acc[5];
      #pragma unroll
      for (int k = 0; k < 5; ++k) acc[k] = pay[k];
      for (unsigned i = 0; i < cnt; ++i){
        int d = idxb[base + i];
        #pragma unroll
        for (int k = 0; k < 5; ++k){
          int v = colbase + k*256 + lane*4;
          acc[k].x += outW[(size_t)(v+0)*D_ + d];
          acc[k].y += outW[(size_t)(v+1)*D_ + d];
          acc[k].z += outW[(size_t)(v+2)*D_ + d];
          acc[k].w += outW[(size_t)(v+3)*D_ + d];
        }
      }
      #pragma unroll
      for (int k = 0; k < 5; ++k)
        __builtin_nontemporal_store(acc[k], (v4f*)(dst + k*256 + lane*4));
    }
  }
}

extern "C" void kernel_launch(void* const* d_in, const int* in_sizes, int n_in,
                              void* d_out, int out_size, void* d_ws, size_t ws_size,
                              hipStream_t stream){
  (void)in_sizes; (void)n_in; (void)out_size; (void)ws_size;
  const int*   input_ids = (const int*)d_in[0];
  const float* embedding = (const float*)d_in[1];
  const float* enc_W = (const float*)d_in[2];
  const float* enc_b = (const float*)d_in[3];
  const float* gen_W = (const float*)d_in[4];
  const float* gen_b = (const float*)d_in[5];
  const float* inf_W = (const float*)d_in[6];
  const float* inf_b = (const float*)d_in[7];
  const float* err_g = (const float*)d_in[8];
  const float* err_b = (const float*)d_in[9];
  const float* st_g  = (const float*)d_in[10];
  const float* st_b  = (const float*)d_in[11];
  const float* out_W = (const float*)d_in[12];
  const float* out_b = (const float*)d_in[13];
  float* out = (float*)d_out;
  char* ws = (char*)d_ws;

  float*          X      = (float*)(ws + 0);                 // 4096*512*4 = 8388608
  unsigned char*  bu     = (unsigned char*)(ws + 8388608);   // 4096*512   = 2097152
  unsigned short* idxb   = (unsigned short*)(ws + 10485760); // 4096*512*2 = 4194304
  unsigned*       counts = (unsigned*)(ws + 14680064);       // 4096*4
  unsigned*       bunz   = (unsigned*)(ws + 14696448);       // 4096*4
  float*          cvec   = (float*)(ws + 14712832);          // 4*512*4
  float*          accum  = (float*)(ws + 14721024);          // 2*4

  hipLaunchKernelGGL(k_gemm_enc, dim3(64, 8), dim3(256), 0, stream,
                     input_ids, embedding, enc_W, enc_b, X, counts, bunz, accum);
  hipLaunchKernelGGL(k_scan, dim3(160), dim3(64), 0, stream,
                     X, bu, bunz, inf_W, inf_b, err_b, cvec);
  hipLaunchKernelGGL(k_sim, dim3(16), dim3(64), 0, stream,
                     gen_W, gen_b, inf_W, inf_b, err_g, err_b, st_g, st_b,
                     bu, bunz, cvec, counts, idxb, accum);
  hipLaunchKernelGGL(k_logits, dim3(3200), dim3(64), 0, stream,
                     counts, idxb, out_W, out_b, accum, out);
}